// Round 1
// baseline (45.780 us; speedup 1.0000x reference)
//
#include <hip/hip_runtime.h>

// Sinusoidal oscillator with FM: out[b,n] = sin(exclusive_cumsum_n(f0_rev*(1+mod_env*amt)) * 2*pi)
// Computed in revolutions; phase scan in f64; hardware v_sin_f32 (input in revolutions).

constexpr int BLOCK = 1024;   // threads per block (one block per row)
constexpr int VPT   = 8;      // values per thread per chunk

__global__ __launch_bounds__(BLOCK) void osc_kernel(
    const float* __restrict__ freq,        // [B]
    const float* __restrict__ mod_env,     // [B, N]
    const float* __restrict__ mod_amount,  // [B]
    float* __restrict__ out,               // [B, N]
    int N)
{
    const int row  = blockIdx.x;
    const int tid  = threadIdx.x;
    const int lane = tid & 63;
    const int wid  = tid >> 6;            // wave id, 0..15

    __shared__ double s_wsum[BLOCK / 64];
    __shared__ double s_woff[BLOCK / 64 + 1];   // exclusive wave offsets; [nw] = chunk total

    // Per-row constants (f64, matching a float64 numpy reference)
    const double f0rev = (20.0 + 1980.0 * (double)freq[row]) / 48000.0;  // rev/sample
    const double amt   = -1.0 + 3.0 * (double)mod_amount[row];
    const double k     = f0rev * amt;     // freq_env_rev = f0rev + me * k

    const float* __restrict__ rowp = mod_env + (size_t)row * N;
    float* __restrict__ outp       = out     + (size_t)row * N;

    const int chunk  = BLOCK * VPT;       // 8192
    const int nchunk = N / chunk;         // N = 65536 -> 8

    double carry = 0.0;

    // Prefetch chunk 0
    const float* p0 = rowp + tid * VPT;
    float4 curA = *(const float4*)(p0);
    float4 curB = *(const float4*)(p0 + 4);

    for (int c = 0; c < nchunk; ++c) {
        // Prefetch next chunk while we compute this one
        float4 nxtA = curA, nxtB = curB;
        if (c + 1 < nchunk) {
            const float* p = rowp + (size_t)(c + 1) * chunk + tid * VPT;
            nxtA = *(const float4*)(p);
            nxtB = *(const float4*)(p + 4);
        }

        // Per-element increments (rev/sample) in f64
        double v0 = fma((double)curA.x, k, f0rev);
        double v1 = fma((double)curA.y, k, f0rev);
        double v2 = fma((double)curA.z, k, f0rev);
        double v3 = fma((double)curA.w, k, f0rev);
        double v4 = fma((double)curB.x, k, f0rev);
        double v5 = fma((double)curB.y, k, f0rev);
        double v6 = fma((double)curB.z, k, f0rev);
        double v7 = fma((double)curB.w, k, f0rev);

        double tsum = ((v0 + v1) + (v2 + v3)) + ((v4 + v5) + (v6 + v7));

        // Wave-level inclusive scan of per-thread sums (f64)
        double x = tsum;
        #pragma unroll
        for (int off = 1; off < 64; off <<= 1) {
            double y = __shfl_up(x, off, 64);
            if (lane >= off) x += y;
        }

        if (lane == 63) s_wsum[wid] = x;
        __syncthreads();

        // Cross-wave scan (16 wave sums) by the first 16 lanes of wave 0
        if (tid < BLOCK / 64) {
            double w  = s_wsum[tid];
            double xs = w;
            #pragma unroll
            for (int off = 1; off < BLOCK / 64; off <<= 1) {
                double y = __shfl_up(xs, off, 64);
                if (tid >= off) xs += y;
            }
            s_woff[tid] = xs - w;                       // exclusive
            if (tid == BLOCK / 64 - 1) s_woff[BLOCK / 64] = xs;  // total
        }
        __syncthreads();

        // Exclusive phase base for this thread (revolutions)
        double phase = carry + s_woff[wid] + (x - tsum);

        float4 oA, oB;
        {
            double pf;
            pf = phase - floor(phase); oA.x = __builtin_amdgcn_sinf((float)pf); phase += v0;
            pf = phase - floor(phase); oA.y = __builtin_amdgcn_sinf((float)pf); phase += v1;
            pf = phase - floor(phase); oA.z = __builtin_amdgcn_sinf((float)pf); phase += v2;
            pf = phase - floor(phase); oA.w = __builtin_amdgcn_sinf((float)pf); phase += v3;
            pf = phase - floor(phase); oB.x = __builtin_amdgcn_sinf((float)pf); phase += v4;
            pf = phase - floor(phase); oB.y = __builtin_amdgcn_sinf((float)pf); phase += v5;
            pf = phase - floor(phase); oB.z = __builtin_amdgcn_sinf((float)pf); phase += v6;
            pf = phase - floor(phase); oB.w = __builtin_amdgcn_sinf((float)pf); phase += v7;
        }

        float* q = outp + (size_t)c * chunk + tid * VPT;
        *(float4*)(q)     = oA;
        *(float4*)(q + 4) = oB;

        carry += s_woff[BLOCK / 64];
        __syncthreads();   // protect s_wsum/s_woff before next chunk overwrites

        curA = nxtA; curB = nxtB;
    }
}

extern "C" void kernel_launch(void* const* d_in, const int* in_sizes, int n_in,
                              void* d_out, int out_size, void* d_ws, size_t ws_size,
                              hipStream_t stream) {
    const float* freq       = (const float*)d_in[1];
    const float* mod_env    = (const float*)d_in[2];
    const float* mod_amount = (const float*)d_in[3];
    float* out = (float*)d_out;

    const int B = in_sizes[1];              // 512
    const int N = in_sizes[2] / B;          // 65536

    osc_kernel<<<B, BLOCK, 0, stream>>>(freq, mod_env, mod_amount, out, N);
}